// Round 1
// baseline (279.585 us; speedup 1.0000x reference)
//
#include <hip/hip_runtime.h>

typedef unsigned short u16;
typedef __bf16  bf16x8 __attribute__((ext_vector_type(8)));
typedef float   f32x4  __attribute__((ext_vector_type(4)));

#define HW    3136        // 56*56
#define NB    32          // batch
#define P_TOT 100352      // NB*HW
#define EPSV  1e-5f

// ---------- helpers ----------
__device__ __forceinline__ u16 f2bf(float f) {           // RNE float->bf16
  unsigned u = __float_as_uint(f);
  u = u + 0x7FFFu + ((u >> 16) & 1u);
  return (u16)(u >> 16);
}

__device__ __forceinline__ void gl_lds16(const void* g, void* l) {
  // async global->LDS, 16B per lane; LDS dest = wave-uniform base + lane*16
  __builtin_amdgcn_global_load_lds((const __attribute__((address_space(1))) void*)g,
                                   (__attribute__((address_space(3))) void*)l, 16, 0, 0);
}

// ---------- K1: fold BN constants, convert weights to bf16 ----------
// w1b[cm][cin] bf16 ; w2b[o][kh*3+kw][cin] bf16 (K-order tap-major, cin-minor)
__global__ __launch_bounds__(256) void k_prep(
    const float* __restrict__ w1, const float* __restrict__ w2,
    const float* __restrict__ g1, const float* __restrict__ be1,
    const float* __restrict__ m1, const float* __restrict__ v1,
    const float* __restrict__ g2, const float* __restrict__ be2,
    const float* __restrict__ m2, const float* __restrict__ v2,
    const float* __restrict__ c1b,
    u16* __restrict__ w1b, u16* __restrict__ w2b,
    float* __restrict__ s1, float* __restrict__ b1,
    float* __restrict__ s2, float* __restrict__ b2, float* __restrict__ zbuf) {
  const int i = blockIdx.x * 256 + threadIdx.x;
  if (i < 32768) w1b[i] = f2bf(w1[i]);                       // [cm][cin] natural (1x1)
  if (i < 36864) {
    const int o = i / 1152, rem = i % 1152, tap = rem >> 7, cin = rem & 127;
    const int kh = tap / 3, kw = tap % 3;
    w2b[i] = f2bf(w2[((o * 128 + cin) * 3 + kh) * 3 + kw]);
  }
  if (i < 256) { float s = g1[i] / sqrtf(v1[i] + EPSV); s1[i] = s; b1[i] = be1[i] - m1[i] * s; }
  else if (i < 384) { int c = i - 256; float s = g2[c] / sqrtf(v2[c] + EPSV);
                      s2[c] = s; b2[c] = be2[c] - m2[c] * s + c1b[c] * s; }
  else if (i < 448) zbuf[i - 384] = 0.f;                     // 256B zero source for halo
}

// ---------- K2: copy x -> out[:,0:256] + t1[pos][cin] = bf16(relu(bn1(x))) ----------
__global__ __launch_bounds__(256) void k_bn1(
    const float* __restrict__ x, const float* __restrict__ s1, const float* __restrict__ b1,
    float* __restrict__ out, u16* __restrict__ t1) {
  __shared__ float lds[64][65];                              // 64 cin x 64 hw, pad 65
  const int t   = threadIdx.x;
  const int hw0 = blockIdx.x * 64;
  const int c0  = blockIdx.y * 64;
  const int n   = blockIdx.z;
  const int cc  = (t & 15) * 4;
  const int r0  = t >> 4;
#pragma unroll
  for (int j = 0; j < 4; ++j) {
    const int r = r0 + j * 16;
    const int cin = c0 + r;
    const float4 v = *(const float4*)(x + (size_t)(n * 256 + cin) * HW + hw0 + cc);
    *(float4*)(out + (size_t)(n * 288 + cin) * HW + hw0 + cc) = v;   // exact copy
    const float s = s1[cin], b = b1[cin];
    lds[r][cc + 0] = fmaxf(v.x * s + b, 0.f);
    lds[r][cc + 1] = fmaxf(v.y * s + b, 0.f);
    lds[r][cc + 2] = fmaxf(v.z * s + b, 0.f);
    lds[r][cc + 3] = fmaxf(v.w * s + b, 0.f);
  }
  __syncthreads();
  const int hwl = t >> 2;
  const int cL  = (t & 3) * 16;
  unsigned pk[8];
#pragma unroll
  for (int j = 0; j < 8; ++j) {
    const u16 lo = f2bf(lds[cL + 2 * j][hwl]);
    const u16 hi = f2bf(lds[cL + 2 * j + 1][hwl]);
    pk[j] = (unsigned)lo | ((unsigned)hi << 16);
  }
  uint4* dst = (uint4*)(t1 + (size_t)(n * HW + hw0 + hwl) * 256 + c0 + cL);
  dst[0] = make_uint4(pk[0], pk[1], pk[2], pk[3]);
  dst[1] = make_uint4(pk[4], pk[5], pk[6], pk[7]);
}

// ---------- K3: 1x1 conv GEMM (M=pos 128/blk, N=cm 128, K=256) + bn2+relu -> t2 ----------
__global__ __launch_bounds__(256) void k_conv1(
    const u16* __restrict__ t1, const u16* __restrict__ w1b,
    const float* __restrict__ s2, const float* __restrict__ b2, u16* __restrict__ t2) {
  __shared__ u16 SA[128 * 64];   // [pos row][64 k] bf16, XOR-swizzled, 128B rows
  __shared__ u16 SB[128 * 64];   // [cm  row][64 k]
  const int tid = threadIdx.x;
  const int l = tid & 63, wv = tid >> 6;
  const size_t pos0 = (size_t)blockIdx.x * 128;
  const int wr = wv >> 1, wc = wv & 1;
  f32x4 acc[4][4] = {};
  const int lrow = l >> 3, lch = l & 7;
  for (int kt = 0; kt < 4; ++kt) {
#pragma unroll
    for (int i = 0; i < 4; ++i) {
      const int row = wv * 32 + i * 8 + lrow;
      const int sw  = (lch ^ (row & 7)) * 8;                 // pre-swizzled source (elems)
      gl_lds16(t1 + (pos0 + row) * 256 + kt * 64 + sw, (char*)SA + (wv * 32 + i * 8) * 128);
      gl_lds16(w1b + row * 256 + kt * 64 + sw,          (char*)SB + (wv * 32 + i * 8) * 128);
    }
    __syncthreads();
#pragma unroll
    for (int kk = 0; kk < 2; ++kk) {
      const int kb = kk * 64 + (l >> 4) * 16;                // byte offset in 128B row
      bf16x8 af[4], bfr[4];
#pragma unroll
      for (int m = 0; m < 4; ++m) {
        const int ra = wr * 64 + m * 16 + (l & 15);
        af[m]  = *(const bf16x8*)((const char*)SA + ra * 128 + (kb ^ ((ra & 7) << 4)));
        const int rb = wc * 64 + m * 16 + (l & 15);
        bfr[m] = *(const bf16x8*)((const char*)SB + rb * 128 + (kb ^ ((rb & 7) << 4)));
      }
#pragma unroll
      for (int m = 0; m < 4; ++m)
#pragma unroll
        for (int nn = 0; nn < 4; ++nn)
          acc[m][nn] = __builtin_amdgcn_mfma_f32_16x16x32_bf16(af[m], bfr[nn], acc[m][nn], 0, 0, 0);
    }
    __syncthreads();
  }
  // epilogue: D row = pos = (l>>4)*4+r (+tiles), D col = cm = l&15 (+tiles)
#pragma unroll
  for (int nn = 0; nn < 4; ++nn) {
    const int cm = wc * 64 + nn * 16 + (l & 15);
    const float s = s2[cm], b = b2[cm];
#pragma unroll
    for (int m = 0; m < 4; ++m)
#pragma unroll
      for (int r = 0; r < 4; ++r) {
        const size_t pos = pos0 + wr * 64 + m * 16 + (l >> 4) * 4 + r;
        t2[pos * 128 + cm] = f2bf(fmaxf(acc[m][nn][r] * s + b, 0.f));
      }
  }
}

// ---------- K4: 3x3 conv as 9 accumulated GEMMs; block = one (n,h) row ----------
__global__ __launch_bounds__(256) void k_conv2(
    const u16* __restrict__ t2, const u16* __restrict__ w2b,
    const float* __restrict__ bias, const float* __restrict__ zbuf, float* __restrict__ out) {
  __shared__ u16 SB[3 * 64 * 128];  // [hr][wl 0..63][128 cin] bf16, swizzled 256B rows
  __shared__ u16 SW[32 * 128];      // per-tap weight slice [o][cin]
  const int tid = threadIdx.x;
  const int l = tid & 63, wv = tid >> 6;
  const int h = blockIdx.x, n = blockIdx.y;
  // stage input halo tile (wl = w_in+1; OOB -> zero buffer)
#pragma unroll
  for (int i = 0; i < 12; ++i) {
    const int q = (wv * 12 + i) * 64 + l;
    const int c = q & 15, wl = (q >> 4) & 63, hr = q >> 10;
    const int h_in = h + hr - 1, w_in = wl - 1;
    const int csrc = (c & 8) | ((c & 7) ^ (wl & 7));
    const bool valid = ((unsigned)h_in < 56u) && ((unsigned)w_in < 56u);
    const u16* src = valid ? t2 + ((size_t)(n * HW) + h_in * 56 + w_in) * 128 + csrc * 8
                           : (const u16*)zbuf;
    gl_lds16(src, (char*)SB + (wv * 12 + i) * 1024);
  }
  // stage tap-0 weights
#pragma unroll
  for (int i = 0; i < 2; ++i) {
    const int q = (wv * 2 + i) * 64 + l;
    const int o = q >> 4, c = q & 15;
    const int csrc = (c & 8) | ((c & 7) ^ (o & 7));
    gl_lds16(w2b + o * 1152 + csrc * 8, (char*)SW + (wv * 2 + i) * 1024);
  }
  __syncthreads();
  f32x4 acc[2] = {};
#pragma unroll
  for (int tap = 0; tap < 9; ++tap) {
    const int kh = tap / 3, kw = tap % 3;
#pragma unroll
    for (int kk = 0; kk < 4; ++kk) {
      const int kb = kk * 64 + (l >> 4) * 16;
      const int wl = wv * 16 + kw + (l & 15);                // = out_w + kw
      const bf16x8 b = *(const bf16x8*)((const char*)SB + (kh * 64 + wl) * 256 + (kb ^ ((wl & 7) << 4)));
#pragma unroll
      for (int mt = 0; mt < 2; ++mt) {
        const int ar = mt * 16 + (l & 15);
        const bf16x8 a = *(const bf16x8*)((const char*)SW + ar * 256 + (kb ^ ((ar & 7) << 4)));
        acc[mt] = __builtin_amdgcn_mfma_f32_16x16x32_bf16(a, b, acc[mt], 0, 0, 0);
      }
    }
    if (tap < 8) {
      __syncthreads();                                       // all waves done with SW
#pragma unroll
      for (int i = 0; i < 2; ++i) {
        const int q = (wv * 2 + i) * 64 + l;
        const int o = q >> 4, c = q & 15;
        const int csrc = (c & 8) | ((c & 7) ^ (o & 7));
        gl_lds16(w2b + o * 1152 + (tap + 1) * 128 + csrc * 8, (char*)SW + (wv * 2 + i) * 1024);
      }
      __syncthreads();
    }
  }
  const int w = wv * 16 + (l & 15);
  if (w < 56) {
#pragma unroll
    for (int mt = 0; mt < 2; ++mt)
#pragma unroll
      for (int r = 0; r < 4; ++r) {
        const int o = mt * 16 + (l >> 4) * 4 + r;
        out[(size_t)(n * 288 + 256 + o) * HW + h * 56 + w] = acc[mt][r] + bias[o];
      }
  }
}

// ---------- launch ----------
extern "C" void kernel_launch(void* const* d_in, const int* in_sizes, int n_in,
                              void* d_out, int out_size, void* d_ws, size_t ws_size,
                              hipStream_t stream) {
  const float* x   = (const float*)d_in[0];
  const float* g1  = (const float*)d_in[1];
  const float* be1 = (const float*)d_in[2];
  const float* m1  = (const float*)d_in[3];
  const float* v1  = (const float*)d_in[4];
  const float* w1  = (const float*)d_in[5];
  const float* c1b = (const float*)d_in[6];
  const float* g2  = (const float*)d_in[7];
  const float* be2 = (const float*)d_in[8];
  const float* m2  = (const float*)d_in[9];
  const float* v2  = (const float*)d_in[10];
  const float* w2  = (const float*)d_in[11];
  const float* c2b = (const float*)d_in[12];
  float* out = (float*)d_out;

  char* ws = (char*)d_ws;
  // ws layout (bytes)
  u16*   t1   = (u16*)(ws + 0);                     // 51,380,224
  u16*   t2   = (u16*)(ws + 51380224);              // 25,690,112
  u16*   w1b  = (u16*)(ws + 77070336);              // 65,536
  u16*   w2b  = (u16*)(ws + 77135872);              // 73,728
  float* s1   = (float*)(ws + 77209600);            // 1,024
  float* b1   = (float*)(ws + 77210624);            // 1,024
  float* s2   = (float*)(ws + 77211648);            // 512
  float* b2   = (float*)(ws + 77212160);            // 512
  float* zbuf = (float*)(ws + 77212672);            // 256

  k_prep<<<dim3(144), dim3(256), 0, stream>>>(w1, w2, g1, be1, m1, v1, g2, be2, m2, v2, c1b,
                                              w1b, w2b, s1, b1, s2, b2, zbuf);
  k_bn1<<<dim3(49, 4, NB), dim3(256), 0, stream>>>(x, s1, b1, out, t1);
  k_conv1<<<dim3(P_TOT / 128), dim3(256), 0, stream>>>(t1, w1b, s2, b2, t2);
  k_conv2<<<dim3(56, NB), dim3(256), 0, stream>>>(t2, w2b, c2b, zbuf, out);
}

// Round 3
// 276.887 us; speedup vs baseline: 1.0097x; 1.0097x over previous
//
#include <hip/hip_runtime.h>

typedef unsigned short u16;
typedef __bf16  bf16x8 __attribute__((ext_vector_type(8)));
typedef float   f32x4  __attribute__((ext_vector_type(4)));

#define HW    3136        // 56*56
#define NB    32          // batch
#define P_TOT 100352      // NB*HW
#define EPSV  1e-5f

// ---------- helpers ----------
__device__ __forceinline__ u16 f2bf(float f) {           // RNE float->bf16
  unsigned u = __float_as_uint(f);
  u = u + 0x7FFFu + ((u >> 16) & 1u);
  return (u16)(u >> 16);
}

__device__ __forceinline__ void gl_lds16(const void* g, void* l) {
  // async global->LDS, 16B per lane; LDS dest = wave-uniform base + lane*16
  __builtin_amdgcn_global_load_lds((const __attribute__((address_space(1))) void*)g,
                                   (__attribute__((address_space(3))) void*)l, 16, 0, 0);
}

// ---------- K1: fold BN constants, convert weights to bf16 ----------
__global__ __launch_bounds__(256) void k_prep(
    const float* __restrict__ w1, const float* __restrict__ w2,
    const float* __restrict__ g1, const float* __restrict__ be1,
    const float* __restrict__ m1, const float* __restrict__ v1,
    const float* __restrict__ g2, const float* __restrict__ be2,
    const float* __restrict__ m2, const float* __restrict__ v2,
    const float* __restrict__ c1b,
    u16* __restrict__ w1b, u16* __restrict__ w2b,
    float* __restrict__ s1, float* __restrict__ b1,
    float* __restrict__ s2, float* __restrict__ b2, float* __restrict__ zbuf) {
  const int i = blockIdx.x * 256 + threadIdx.x;
  if (i < 32768) w1b[i] = f2bf(w1[i]);                       // [cm][cin] natural (1x1)
  if (i < 36864) {
    const int o = i / 1152, rem = i % 1152, tap = rem >> 7, cin = rem & 127;
    const int kh = tap / 3, kw = tap % 3;
    w2b[i] = f2bf(w2[((o * 128 + cin) * 3 + kh) * 3 + kw]);
  }
  if (i < 256) { float s = g1[i] / sqrtf(v1[i] + EPSV); s1[i] = s; b1[i] = be1[i] - m1[i] * s; }
  else if (i < 384) { int c = i - 256; float s = g2[c] / sqrtf(v2[c] + EPSV);
                      s2[c] = s; b2[c] = be2[c] - m2[c] * s + c1b[c] * s; }
  else if (i < 448) zbuf[i - 384] = 0.f;                     // 256B zero source for halo
}

// ---------- K2: copy x -> out[:,0:256] + t1[pos][256c] bf16(relu(bn1(x))) ----------
// block = (hw-chunk of 64, n); owns ALL 256 channels -> t1 rows written whole.
__global__ __launch_bounds__(256) void k_bn1(
    const float* __restrict__ x, const float* __restrict__ s1, const float* __restrict__ b1,
    float* __restrict__ out, u16* __restrict__ t1) {
  __shared__ float lds[256][65];                             // 66,560 B -> 2 blocks/CU
  const int t   = threadIdx.x;
  const int hw0 = blockIdx.x * 64;
  const int n   = blockIdx.y;
  // phase 1: coalesced load (256B per c-group per instr), copy to out, BN+ReLU -> LDS
  const int p4 = (t & 15) * 4;
  const int cb = t >> 4;                                     // 0..15
#pragma unroll
  for (int j = 0; j < 16; ++j) {
    const int c = cb + j * 16;
    const float4 v = *(const float4*)(x + (size_t)(n * 256 + c) * HW + hw0 + p4);
    *(float4*)(out + (size_t)(n * 288 + c) * HW + hw0 + p4) = v;   // exact copy
    const float s = s1[c], b = b1[c];
    *(float4*)&lds[c][p4] = make_float4(fmaxf(v.x * s + b, 0.f), fmaxf(v.y * s + b, 0.f),
                                        fmaxf(v.z * s + b, 0.f), fmaxf(v.w * s + b, 0.f));
  }
  __syncthreads();
  // phase 2: transpose-pack; each 512B t1 row fully written by 4 threads
  const int hwl = t >> 2;                                    // 0..63
  const int cL  = (t & 3) * 16;                              // 0,16,32,48
#pragma unroll
  for (int q = 0; q < 4; ++q) {
    const int c0 = q * 64 + cL;
    unsigned pk[8];
#pragma unroll
    for (int j = 0; j < 8; ++j)
      pk[j] = (unsigned)f2bf(lds[c0 + 2 * j][hwl]) | ((unsigned)f2bf(lds[c0 + 2 * j + 1][hwl]) << 16);
    uint4* dst = (uint4*)(t1 + (size_t)(n * HW + hw0 + hwl) * 256 + c0);
    dst[0] = make_uint4(pk[0], pk[1], pk[2], pk[3]);
    dst[1] = make_uint4(pk[4], pk[5], pk[6], pk[7]);
  }
}

// ---------- K3: 1x1 conv GEMM (M=pos 128, N=cm 128, K=256) + bn2+relu -> t2 ----------
// 2-phase double-buffer: stage kt+1 before computing kt; 1 barrier per K-step.
__global__ __launch_bounds__(256) void k_conv1(
    const u16* __restrict__ t1, const u16* __restrict__ w1b,
    const float* __restrict__ s2, const float* __restrict__ b2, u16* __restrict__ t2) {
  __shared__ u16 SA[2][128 * 64];  // [pos][64k] swizzled 128B rows
  __shared__ u16 SB[2][128 * 64];  // [cm ][64k]
  const int tid = threadIdx.x;
  const int l = tid & 63, wv = tid >> 6;
  const size_t pos0 = (size_t)blockIdx.x * 128;
  const int wr = wv >> 1, wc = wv & 1;
  const int lrow = l >> 3, lch = l & 7;
  f32x4 acc[4][4] = {};
#pragma unroll
  for (int i = 0; i < 4; ++i) {                              // prologue: stage kt=0
    const int row = wv * 32 + i * 8 + lrow;
    const int sw  = (lch ^ (row & 7)) * 8;
    gl_lds16(t1 + (pos0 + row) * 256 + sw, (char*)SA[0] + (wv * 32 + i * 8) * 128);
    gl_lds16(w1b + row * 256 + sw,          (char*)SB[0] + (wv * 32 + i * 8) * 128);
  }
  __syncthreads();
  for (int kt = 0; kt < 4; ++kt) {
    const int buf = kt & 1;
    if (kt < 3) {                                            // stage next tile first
#pragma unroll
      for (int i = 0; i < 4; ++i) {
        const int row = wv * 32 + i * 8 + lrow;
        const int sw  = (lch ^ (row & 7)) * 8;
        gl_lds16(t1 + (pos0 + row) * 256 + (kt + 1) * 64 + sw, (char*)SA[buf ^ 1] + (wv * 32 + i * 8) * 128);
        gl_lds16(w1b + row * 256 + (kt + 1) * 64 + sw,          (char*)SB[buf ^ 1] + (wv * 32 + i * 8) * 128);
      }
    }
#pragma unroll
    for (int kk = 0; kk < 2; ++kk) {
      const int kb = kk * 64 + (l >> 4) * 16;
      bf16x8 af[4], bfr[4];
#pragma unroll
      for (int m = 0; m < 4; ++m) {
        const int ra = wr * 64 + m * 16 + (l & 15);
        af[m]  = *(const bf16x8*)((const char*)SA[buf] + ra * 128 + (kb ^ ((ra & 7) << 4)));
        const int rb = wc * 64 + m * 16 + (l & 15);
        bfr[m] = *(const bf16x8*)((const char*)SB[buf] + rb * 128 + (kb ^ ((rb & 7) << 4)));
      }
#pragma unroll
      for (int m = 0; m < 4; ++m)
#pragma unroll
        for (int nn = 0; nn < 4; ++nn)
          acc[m][nn] = __builtin_amdgcn_mfma_f32_16x16x32_bf16(af[m], bfr[nn], acc[m][nn], 0, 0, 0);
    }
    if (kt < 3) __syncthreads();
  }
  // epilogue: D row = pos, D col = cm
#pragma unroll
  for (int nn = 0; nn < 4; ++nn) {
    const int cm = wc * 64 + nn * 16 + (l & 15);
    const float s = s2[cm], b = b2[cm];
#pragma unroll
    for (int m = 0; m < 4; ++m)
#pragma unroll
      for (int r = 0; r < 4; ++r) {
        const size_t pos = pos0 + wr * 64 + m * 16 + (l >> 4) * 4 + r;
        t2[pos * 128 + cm] = f2bf(fmaxf(acc[m][nn][r] * s + b, 0.f));
      }
  }
}

// ---------- K4: 3x3 conv; block = (n, 3 h-rows), 12 waves, single barrier ----------
// Stage ALL 9 weight taps (72KB) + 5-row halo (80KB) once: 152KB LDS, 1 block/CU.
__global__ __launch_bounds__(768) void k_conv2(
    const u16* __restrict__ t2, const u16* __restrict__ w2b,
    const float* __restrict__ bias, const float* __restrict__ zbuf, float* __restrict__ out) {
  __shared__ u16 SH[5 * 64 * 128];  // halo [hr][wl][128c], swizzled 256B rows (81,920 B)
  __shared__ u16 SW[9 * 32 * 128];  // weights [tap][o][c]            (73,728 B)
  const int tid = threadIdx.x;
  const int l = tid & 63, wv = tid >> 6;                     // wv 0..11
  const int h0 = blockIdx.x * 3, n = blockIdx.y;
  // ---- stage: 80 halo chunks + 72 weight chunks (1KB each) across 12 waves ----
  for (int i = 0;; ++i) {
    const int ch = wv + i * 12;
    if (ch >= 152) break;
    if (ch < 80) {
      const int hr = ch >> 4, w16 = ch & 15;
      const int wl = w16 * 4 + (l >> 4);
      const int c8 = l & 15;
      const int h_in = h0 + hr - 1, w_in = wl - 1;
      const int csrc = (c8 & 8) | ((c8 & 7) ^ (wl & 7));
      const bool valid = ((unsigned)h_in < 56u) && ((unsigned)w_in < 56u);
      const u16* src = valid ? t2 + ((size_t)(n * HW) + h_in * 56 + w_in) * 128 + csrc * 8
                             : (const u16*)zbuf;
      gl_lds16(src, (char*)SH + ch * 1024);
    } else {
      const int c2 = ch - 80;
      const int tap = c2 >> 3, o4 = c2 & 7;
      const int o = o4 * 4 + (l >> 4), c8 = l & 15;
      const int csrc = (c8 & 8) | ((c8 & 7) ^ (o & 7));
      gl_lds16(w2b + o * 1152 + tap * 128 + csrc * 8, (char*)SW + c2 * 1024);
    }
  }
  __syncthreads();
  // ---- compute: wave = (row r, w-quarter wq); 72 MFMAs, no further barriers ----
  const int r = wv >> 2, wq = wv & 3;
  f32x4 acc[2] = {};
#pragma unroll
  for (int kh = 0; kh < 3; ++kh)
#pragma unroll
    for (int kw = 0; kw < 3; ++kw) {
      const int tap = kh * 3 + kw;
      const int wl = wq * 16 + kw + (l & 15);                // = out_w + kw
#pragma unroll
      for (int kk = 0; kk < 4; ++kk) {
        const int kb = kk * 64 + (l >> 4) * 16;
        const bf16x8 b = *(const bf16x8*)((const char*)SH + ((r + kh) * 64 + wl) * 256 + (kb ^ ((wl & 7) << 4)));
#pragma unroll
        for (int mt = 0; mt < 2; ++mt) {
          const int ar = mt * 16 + (l & 15);
          const bf16x8 a = *(const bf16x8*)((const char*)SW + (tap * 32 + ar) * 256 + (kb ^ ((ar & 7) << 4)));
          acc[mt] = __builtin_amdgcn_mfma_f32_16x16x32_bf16(a, b, acc[mt], 0, 0, 0);
        }
      }
    }
  const int h = h0 + r, w = wq * 16 + (l & 15);
  if (h < 56 && w < 56) {
#pragma unroll
    for (int mt = 0; mt < 2; ++mt)
#pragma unroll
      for (int rr = 0; rr < 4; ++rr) {
        const int o = mt * 16 + (l >> 4) * 4 + rr;
        out[(size_t)(n * 288 + 256 + o) * HW + h * 56 + w] = acc[mt][rr] + bias[o];
      }
  }
}

// ---------- launch ----------
extern "C" void kernel_launch(void* const* d_in, const int* in_sizes, int n_in,
                              void* d_out, int out_size, void* d_ws, size_t ws_size,
                              hipStream_t stream) {
  const float* x   = (const float*)d_in[0];
  const float* g1  = (const float*)d_in[1];
  const float* be1 = (const float*)d_in[2];
  const float* m1  = (const float*)d_in[3];
  const float* v1  = (const float*)d_in[4];
  const float* w1  = (const float*)d_in[5];
  const float* c1b = (const float*)d_in[6];
  const float* g2  = (const float*)d_in[7];
  const float* be2 = (const float*)d_in[8];
  const float* m2  = (const float*)d_in[9];
  const float* v2  = (const float*)d_in[10];
  const float* w2  = (const float*)d_in[11];
  const float* c2b = (const float*)d_in[12];
  float* out = (float*)d_out;

  char* ws = (char*)d_ws;
  u16*   t1   = (u16*)(ws + 0);                     // 51,380,224
  u16*   t2   = (u16*)(ws + 51380224);              // 25,690,112
  u16*   w1b  = (u16*)(ws + 77070336);              // 65,536
  u16*   w2b  = (u16*)(ws + 77135872);              // 73,728
  float* s1   = (float*)(ws + 77209600);            // 1,024
  float* b1   = (float*)(ws + 77210624);            // 1,024
  float* s2   = (float*)(ws + 77211648);            // 512
  float* b2   = (float*)(ws + 77212160);            // 512
  float* zbuf = (float*)(ws + 77212672);            // 256

  k_prep<<<dim3(144), dim3(256), 0, stream>>>(w1, w2, g1, be1, m1, v1, g2, be2, m2, v2, c1b,
                                              w1b, w2b, s1, b1, s2, b2, zbuf);
  k_bn1<<<dim3(49, NB), dim3(256), 0, stream>>>(x, s1, b1, out, t1);
  k_conv1<<<dim3(P_TOT / 128), dim3(256), 0, stream>>>(t1, w1b, s2, b2, t2);
  k_conv2<<<dim3(19, NB), dim3(768), 0, stream>>>(t2, w2b, c2b, zbuf, out);
}